// Round 1
// 54.365 us; speedup vs baseline: 1.0087x; 1.0087x over previous
//
#include <hip/hip_runtime.h>
#include <math.h>

// Quanvolution collapses analytically:
//   per patch p (9 pixels x_j, row-major 3x3), z_j = cos(w_j)*cos(pi*x_j)
//   ev0 = z1*z2*...*z8 ; ev1 = z0*z1 ; ev2 = z0*z1*z2 ; ev3 = z0*z1*z2*z3
//   out[h][w][f] = sum_c ev_f(patch(c,h,w)), flat layout [94][94][4]
// (Heisenberg propagation of Z_j through the CNOT ring of BasicEntanglerLayers;
//  RX layer keeps the product state, so expvals factorize.)
//
// Perf note: kernel is launch-latency-bound (~5 us device time inside a ~55 us
// timed window dominated by the harness's 268 MB poison-fill at 85% HBM peak).
// This revision removes the per-pixel range-reduction (input is in [0,1), so
// cos(pi*x) = v_cos_f32(0.5*x) directly) and uses 64-thread blocks so the 139
// blocks spread cold HBM misses across more CUs.

#define KS   3
#define FOUT 4
#define HIN  96
#define HOUT 94
#define CIN  3

__device__ __forceinline__ float cospi_unit(float v) {
    // v in [0,1]: v_cos_f32 computes cos(2*pi*s0); arg 0.5*v in [0,0.5] needs
    // no v_fract range reduction. Same HW instruction __cosf bottoms out in,
    // so precision is identical to the previously-passing version.
    return __builtin_amdgcn_cosf(0.5f * v);
}

__global__ __launch_bounds__(64) void quanv_kernel(const float* __restrict__ x,
                                                   const float* __restrict__ w,
                                                   float* __restrict__ out) {
    int idx = blockIdx.x * blockDim.x + threadIdx.x;
    if (idx >= HOUT * HOUT) return;
    int h  = idx / HOUT;
    int wc = idx - h * HOUT;

    // cos of RX weights (9 scalars, uniform; w in [0,2pi] so keep full __cosf)
    float cw[9];
#pragma unroll
    for (int j = 0; j < 9; ++j) cw[j] = __cosf(w[j]);
    const float W1 = cw[0] * cw[1];
    const float W2 = W1 * cw[2];
    const float W3 = W2 * cw[3];
    const float W0 = cw[1] * cw[2] * cw[3] * cw[4] * cw[5] * cw[6] * cw[7] * cw[8];

    float acc0 = 0.f, acc1 = 0.f, acc2 = 0.f, acc3 = 0.f;

#pragma unroll
    for (int c = 0; c < CIN; ++c) {
        const float* xc = x + c * HIN * HIN + h * HIN + wc;
        float p[9];
#pragma unroll
        for (int kr = 0; kr < KS; ++kr) {
#pragma unroll
            for (int kc = 0; kc < KS; ++kc) {
                p[kr * KS + kc] = cospi_unit(xc[kr * HIN + kc]);
            }
        }
        const float pr01   = p[0] * p[1];
        const float pr012  = pr01 * p[2];
        const float pr0123 = pr012 * p[3];
        const float pr18   = p[1] * p[2] * p[3] * p[4] * p[5] * p[6] * p[7] * p[8];
        acc0 += W0 * pr18;
        acc1 += W1 * pr01;
        acc2 += W2 * pr012;
        acc3 += W3 * pr0123;
    }

    reinterpret_cast<float4*>(out)[idx] = make_float4(acc0, acc1, acc2, acc3);
}

extern "C" void kernel_launch(void* const* d_in, const int* in_sizes, int n_in,
                              void* d_out, int out_size, void* d_ws, size_t ws_size,
                              hipStream_t stream) {
    const float* x = (const float*)d_in[0];     // [1,3,96,96] fp32
    const float* w = (const float*)d_in[1];     // [1,9] fp32
    float* out = (float*)d_out;                 // [1,4,94,94] fp32 (flat = [94][94][4])

    const int n = HOUT * HOUT;                  // 8836
    dim3 block(64);
    dim3 grid((n + 63) / 64);                   // 139 blocks -> ~139 CUs touched
    hipLaunchKernelGGL(quanv_kernel, grid, block, 0, stream, x, w, out);
}